// Round 26
// baseline (38.746 us; speedup 1.0000x reference)
//
#include <hip/hip_runtime.h>
#include <stdint.h>

#define NB 524288
#define NC 32
#define EPSV 1e-4f
#define DTB 0.12f      // DT * BETA
#define CLAMPV 3.0f
#define NSTEPS 4

typedef float f32x16 __attribute__((ext_vector_type(16)));
typedef short short8 __attribute__((ext_vector_type(8)));

union FragU { uint32_t u[4]; short8 s; uint4 q; };

__device__ __forceinline__ uint32_t pkbf16(float a, float b) {
    uint32_t r;
    asm("v_cvt_pk_bf16_f32 %0, %1, %2" : "=v"(r) : "v"(a), "v"(b));
    return r;   // low16 = bf16(a), high16 = bf16(b)
}
__device__ __forceinline__ float lo16f(uint32_t w) { return __uint_as_float(w << 16); }
__device__ __forceinline__ float hi16f(uint32_t w) { return __uint_as_float(w & 0xffff0000u); }
__device__ __forceinline__ float bfh(float v) { return lo16f(pkbf16(v, v)); } // RTN bf16 as f32
__device__ __forceinline__ float sx32(float v) { return __shfl_xor(v, 32); }

// r24-exact (best passing config: absmax 0.015625):
//   GEMM1: k-embedded full 4-term split, 2 MFMAs (B1: hi0 = z_hi dims 0-7 natural order,
//          hi1 = z_lo dims 0-7 natural order via zb-first reorder).
//   bb + zz terms in fp32 per-lane tables (exact).
//   GEMM2: two independent 4-chains (chunk0/chunk1), w3 hi + lo residual (load-bearing, r25).
// ws layout:
//  uint4 [0..63]    A1f1 | [64..127] A1f2
//  uint4 [128..191] A2_hi chunk0 (k-permuted: center(ch,k) = ch*16 + (k&3)+8*((k>>2)&1)+4*(k>>3))
//  uint4 [192..255] A2_hi chunk1 | [256..319] A2_lo chunk0 | [320..383] A2_lo chunk1
//  float [1536..1567] imtab: 1/mu^2 of center crow(r,h)=(r&3)+8*(r>>2)+4*h
//  float [1568..1599] bbtab: (|c|^2+eps)/mu^2 of the same center (fp32-exact)
__global__ void prep_kernel(const float* __restrict__ centers,
                            const float* __restrict__ mus,
                            uint4* __restrict__ wsu) {
    int t = threadIdx.x;
    if (t >= 64) return;
    int row = t & 31, part = t >> 5;

    // ---- A1 fragments (k-embedded hi/lo split) ----
    {
        float mu = mus[row];
        float im2 = 1.0f / (mu * mu);
        float vh[8], vl[8];
        #pragma unroll
        for (int d = 0; d < 8; ++d) {
            float v = -2.0f * centers[row * 8 + d] * im2;
            float h = bfh(v);
            vh[d] = h;
            vl[d] = v - h;
        }
        uint4 f1, f2;
        const float* e1 = (part == 0) ? vh : vl;
        const float* e2 = (part == 0) ? vl : vh;
        f1.x = pkbf16(e1[0], e1[1]); f1.y = pkbf16(e1[2], e1[3]);
        f1.z = pkbf16(e1[4], e1[5]); f1.w = pkbf16(e1[6], e1[7]);
        f2.x = pkbf16(e2[0], e2[1]); f2.y = pkbf16(e2[2], e2[3]);
        f2.z = pkbf16(e2[4], e2[5]); f2.w = pkbf16(e2[6], e2[7]);
        wsu[t]      = f1;
        wsu[64 + t] = f2;
    }

    // ---- A2 (rows 0-7 = c_d/mu^2, row 8 = 1/mu^2; k-axis permuted) ----
    #pragma unroll
    for (int ch = 0; ch < 2; ++ch) {
        float v2[8];
        #pragma unroll
        for (int i = 0; i < 8; ++i) {
            int k = part * 8 + i;
            int within = (k & 3) + 8 * ((k >> 2) & 1) + 4 * (k >> 3);
            int ci = ch * 16 + within;
            float muc = mus[ci];
            float im2c = 1.0f / (muc * muc);
            v2[i] = (row < 8) ? (centers[ci * 8 + row] * im2c) : (row == 8) ? im2c : 0.0f;
        }
        uint32_t h2[4], l2[4];
        #pragma unroll
        for (int j = 0; j < 4; ++j) {
            float a = v2[2 * j], b = v2[2 * j + 1];
            h2[j] = pkbf16(a, b);
            l2[j] = pkbf16(a - lo16f(h2[j]), b - hi16f(h2[j]));
        }
        wsu[128 + ch * 64 + t] = make_uint4(h2[0], h2[1], h2[2], h2[3]);
        wsu[256 + ch * 64 + t] = make_uint4(l2[0], l2[1], l2[2], l2[3]);
    }

    // ---- imtab + bbtab (fp32-exact) ----
    if (t < 32) {
        int h2i = t >> 4, r = t & 15;
        int ci = (r & 3) + 8 * (r >> 2) + 4 * h2i;
        float muc = mus[ci];
        float im2c = 1.0f / (muc * muc);
        float bbc = EPSV;
        #pragma unroll
        for (int d = 0; d < 8; ++d) {
            float cd = centers[ci * 8 + d];
            bbc = fmaf(cd, cd, bbc);
        }
        ((float*)wsu)[1536 + t] = im2c;
        ((float*)wsu)[1568 + t] = bbc * im2c;
    }
}

__global__ __launch_bounds__(256, 4) void pm_kernel(
    const float* __restrict__ z_in,
    const uint4* __restrict__ wsu,
    float* __restrict__ out)
{
    const int tid  = threadIdx.x;
    const int wid  = tid >> 6;
    const int lane = tid & 63;
    const int hi   = lane >> 5;          // half-wave id
    const int col  = lane & 31;          // point within tile
    const int point = blockIdx.x * 128 + wid * 32 + col;

    // constant fragments (L2-resident)
    FragU A1f1, A1f2, A2h0, A2h1, A2l0, A2l1;
    A1f1.q = wsu[lane];        A1f2.q = wsu[64 + lane];
    A2h0.q = wsu[128 + lane];  A2h1.q = wsu[192 + lane];
    A2l0.q = wsu[256 + lane];  A2l1.q = wsu[320 + lane];

    // per-lane fp32 constants for centers crow(r,hi): imv = 1/mu^2, bbt = (|c|^2+eps)/mu^2
    const float* imt = ((const float*)wsu) + 1536 + hi * 16;
    const float* bbp = ((const float*)wsu) + 1568 + hi * 16;
    float imv[16], bbt[16];
    #pragma unroll
    for (int r = 0; r < 16; ++r) { imv[r] = imt[r]; bbt[r] = bbp[r]; }

    // z: this lane owns dims [hi*4 .. hi*4+3] (za); partner half via shfl (zb)
    const float4* zp4 = (const float4*)z_in;
    float4 hvec = zp4[(size_t)point * 2 + hi];
    float za0 = hvec.x, za1 = hvec.y, za2 = hvec.z, za3 = hvec.w;
    float zb0 = sx32(za0), zb1 = sx32(za1), zb2 = sx32(za2), zb3 = sx32(za3);

    #pragma unroll
    for (int s = 0; s < NSTEPS; ++s) {
        // zz = |z|^2 (fp32)
        float zz = za0 * za0;
        zz = fmaf(za1, za1, zz); zz = fmaf(za2, za2, zz); zz = fmaf(za3, za3, zz);
        zz = fmaf(zb0, zb0, zz); zz = fmaf(zb1, zb1, zz);
        zz = fmaf(zb2, zb2, zz); zz = fmaf(zb3, zb3, zz);

        // ---- B1 (single fragment), k-slots = dims 0..7 natural order ----
        // hi0 lane: za = dims 0-3, zb = dims 4-7 -> h0,h1,h2,h3
        // hi1 lane: za = dims 4-7, zb = dims 0-3 -> l2,l3,l0,l1 (zb-first reorder)
        uint32_t h0 = pkbf16(za0, za1), h1 = pkbf16(za2, za3);
        uint32_t h2 = pkbf16(zb0, zb1), h3 = pkbf16(zb2, zb3);
        uint32_t l0 = pkbf16(za0 - lo16f(h0), za1 - hi16f(h0));
        uint32_t l1 = pkbf16(za2 - lo16f(h1), za3 - hi16f(h1));
        uint32_t l2 = pkbf16(zb0 - lo16f(h2), zb1 - hi16f(h2));
        uint32_t l3 = pkbf16(zb2 - lo16f(h3), zb3 - hi16f(h3));

        FragU B1;
        B1.u[0] = hi ? l2 : h0;
        B1.u[1] = hi ? l3 : h1;
        B1.u[2] = hi ? l0 : h2;
        B1.u[3] = hi ? l1 : h3;

        // ---- GEMM1: 2 MFMAs, full 4-term split via k-embedding ----
        f32x16 D1 = {};
        D1 = __builtin_amdgcn_mfma_f32_32x32x16_bf16(A1f1.s, B1.s, D1, 0, 0, 0);
        D1 = __builtin_amdgcn_mfma_f32_32x32x16_bf16(A1f2.s, B1.s, D1, 0, 0, 0);

        // ---- elementwise: r2' = D1 + bb/mu^2 + zz/mu^2 (fp32) ; w = rsq = mu/r ----
        float wv[16];
        #pragma unroll
        for (int r = 0; r < 16; ++r) {
            float r2 = fmaf(zz, imv[r], D1[r] + bbt[r]);
            wv[r] = __builtin_amdgcn_rsqf(r2);
        }
        float t0 = wv[0] + wv[1],   t1 = wv[2] + wv[3],   t2 = wv[4] + wv[5],   t3 = wv[6] + wv[7];
        float t4 = wv[8] + wv[9],   t5 = wv[10] + wv[11], t6 = wv[12] + wv[13], t7 = wv[14] + wv[15];
        float n_half = ((t0 + t1) + (t2 + t3)) + ((t4 + t5) + (t6 + t7));
        float w3v[16];
        #pragma unroll
        for (int r = 0; r < 16; ++r) w3v[r] = (wv[r] * wv[r]) * wv[r];

        // ---- B2 pack: pure local, hi + lo residual (load-bearing per r25) ----
        FragU B2c0h, B2c1h, B2c0l, B2c1l;
        #pragma unroll
        for (int j = 0; j < 4; ++j) {
            float a = w3v[2 * j], b = w3v[2 * j + 1];
            uint32_t ph = pkbf16(a, b);
            B2c0h.u[j] = ph;
            B2c0l.u[j] = pkbf16(a - lo16f(ph), b - hi16f(ph));
        }
        #pragma unroll
        for (int j = 0; j < 4; ++j) {
            float a = w3v[8 + 2 * j], b = w3v[8 + 2 * j + 1];
            uint32_t ph = pkbf16(a, b);
            B2c1h.u[j] = ph;
            B2c1l.u[j] = pkbf16(a - lo16f(ph), b - hi16f(ph));
        }

        // ---- GEMM2: two INDEPENDENT 4-chains (chunk0 / chunk1), fp32 merge ----
        f32x16 D2a = {}, D2b = {};
        D2a = __builtin_amdgcn_mfma_f32_32x32x16_bf16(A2h0.s, B2c0h.s, D2a, 0, 0, 0);
        D2b = __builtin_amdgcn_mfma_f32_32x32x16_bf16(A2h1.s, B2c1h.s, D2b, 0, 0, 0);
        D2a = __builtin_amdgcn_mfma_f32_32x32x16_bf16(A2l0.s, B2c0h.s, D2a, 0, 0, 0);
        D2b = __builtin_amdgcn_mfma_f32_32x32x16_bf16(A2l1.s, B2c1h.s, D2b, 0, 0, 0);
        D2a = __builtin_amdgcn_mfma_f32_32x32x16_bf16(A2h0.s, B2c0l.s, D2a, 0, 0, 0);
        D2b = __builtin_amdgcn_mfma_f32_32x32x16_bf16(A2h1.s, B2c1l.s, D2b, 0, 0, 0);
        D2a = __builtin_amdgcn_mfma_f32_32x32x16_bf16(A2l0.s, B2c0l.s, D2a, 0, 0, 0);
        D2b = __builtin_amdgcn_mfma_f32_32x32x16_bf16(A2l1.s, B2c1l.s, D2b, 0, 0, 0);

        // ---- epilogue ----
        float n  = 1.0f + n_half + sx32(n_half);
        float swp = D2a[4] + D2b[4];          // hi0: row8 = sw ; hi1: row12 = 0
        float sw = swp + sx32(swp);
        float scale = DTB * __builtin_amdgcn_rcpf(n);

        float g0 = fmaf(-sw, za0, D2a[0] + D2b[0]);
        float g1 = fmaf(-sw, za1, D2a[1] + D2b[1]);
        float g2 = fmaf(-sw, za2, D2a[2] + D2b[2]);
        float g3 = fmaf(-sw, za3, D2a[3] + D2b[3]);
        za0 = fminf(fmaxf(fmaf(scale, g0, za0), -CLAMPV), CLAMPV);
        za1 = fminf(fmaxf(fmaf(scale, g1, za1), -CLAMPV), CLAMPV);
        za2 = fminf(fmaxf(fmaf(scale, g2, za2), -CLAMPV), CLAMPV);
        za3 = fminf(fmaxf(fmaf(scale, g3, za3), -CLAMPV), CLAMPV);
        zb0 = sx32(za0); zb1 = sx32(za1); zb2 = sx32(za2); zb3 = sx32(za3);
    }

    float4* op = (float4*)out;
    op[(size_t)point * 2 + hi] = make_float4(za0, za1, za2, za3);
}

extern "C" void kernel_launch(void* const* d_in, const int* in_sizes, int n_in,
                              void* d_out, int out_size, void* d_ws, size_t ws_size,
                              hipStream_t stream) {
    const float* z       = (const float*)d_in[0];
    const float* centers = (const float*)d_in[1];
    const float* mus     = (const float*)d_in[2];
    float* out           = (float*)d_out;
    uint4* wsu           = (uint4*)d_ws;

    prep_kernel<<<1, 64, 0, stream>>>(centers, mus, wsu);
    pm_kernel<<<NB / 128, 256, 0, stream>>>(z, wsu, out);   // 4096 blocks, 32 pts/wave
}